// Round 1
// baseline (1444.861 us; speedup 1.0000x reference)
//
#include <hip/hip_runtime.h>
#include <hip/hip_bf16.h>

#define N_NODES 50000
#define N_EDGES 800000
#define N_GRAPHS 500
#define DIM 128
#define EDIM 7
#define LAYERS 5
#define NCLASS 10
#define BN_EPS 1e-5f
#define TM 64   // rows per GEMM block

// ---------------- CSR build ----------------

__global__ void zero_ints(int* __restrict__ p, int n) {
    int i = blockIdx.x * 256 + threadIdx.x;
    if (i < n) p[i] = 0;
}

__global__ void hist_kernel(const int* __restrict__ dst, int* __restrict__ deg) {
    int e = blockIdx.x * 256 + threadIdx.x;
    if (e < N_EDGES) atomicAdd(&deg[dst[e]], 1);
}

// single-block exclusive scan over N_NODES, wave-shuffle based
__global__ void scan_kernel(const int* __restrict__ deg, int* __restrict__ row_off) {
    __shared__ int wsum[16];
    __shared__ int carry;
    int t = threadIdx.x;
    int lane = t & 63, wid = t >> 6;
    if (t == 0) carry = 0;
    __syncthreads();
    for (int base = 0; base < N_NODES; base += 1024) {
        int i = base + t;
        int v = (i < N_NODES) ? deg[i] : 0;
        // wave inclusive scan
        int s = v;
        #pragma unroll
        for (int off = 1; off < 64; off <<= 1) {
            int u = __shfl_up(s, off, 64);
            if (lane >= off) s += u;
        }
        if (lane == 63) wsum[wid] = s;
        __syncthreads();
        if (wid == 0) {
            int ws = (lane < 16) ? wsum[lane] : 0;
            int ss = ws;
            #pragma unroll
            for (int off2 = 1; off2 < 16; off2 <<= 1) {
                int u = __shfl_up(ss, off2, 64);
                if (lane >= off2) ss += u;
            }
            if (lane < 16) wsum[lane] = ss - ws;  // exclusive wave offsets
        }
        __syncthreads();
        int incl = s + wsum[wid];
        int excl = incl - v;
        if (i < N_NODES) row_off[i] = carry + excl;
        __syncthreads();                 // everyone has read carry
        if (t == 1023) carry += incl;    // chunk total (padding v=0 keeps this exact)
        __syncthreads();
    }
    if (t == 0) row_off[N_NODES] = carry;
}

__global__ void fill_csr(const int* __restrict__ dst, const int* __restrict__ row_off,
                         int* __restrict__ cursor, int* __restrict__ csr_edges) {
    int e = blockIdx.x * 256 + threadIdx.x;
    if (e < N_EDGES) {
        int d = dst[e];
        int pos = atomicAdd(&cursor[d], 1);
        csr_edges[row_off[d] + pos] = e;
    }
}

// ---------------- node init ----------------

__global__ void init_x(float* __restrict__ x, const float* __restrict__ emb) {
    int i = blockIdx.x * 256 + threadIdx.x;
    if (i < N_NODES * DIM) x[i] = emb[i & (DIM - 1)];
}

// ---------------- aggregation (GINEConv message+sum, fused edge linear) ----------------
// one block per node, thread = feature d; acc starts at x[n] so h = x + agg.

__global__ __launch_bounds__(128)
void aggregate(const float* __restrict__ x, float* __restrict__ h,
               const float* __restrict__ edge_attr,
               const int* __restrict__ src,
               const int* __restrict__ csr_edges,
               const int* __restrict__ row_off,
               const float* __restrict__ eW, const float* __restrict__ eb) {
    __shared__ float Ws[EDIM * DIM];
    int d = threadIdx.x;
    int n = blockIdx.x;
    #pragma unroll
    for (int k = 0; k < EDIM; ++k) Ws[k * DIM + d] = eW[k * DIM + d];
    __syncthreads();
    float bd = eb[d];
    float acc = x[n * DIM + d];
    int beg = row_off[n], end = row_off[n + 1];
    for (int idx = beg; idx < end; ++idx) {
        int e = csr_edges[idx];
        int s = src[e];
        const float* ea = edge_attr + e * EDIM;
        float ed = bd;
        #pragma unroll
        for (int k = 0; k < EDIM; ++k) ed += ea[k] * Ws[k * DIM + d];
        float m = x[s * DIM + d] + ed;
        acc += fmaxf(m, 0.f);
    }
    h[n * DIM + d] = acc;
}

// ---------------- GEMM + bias + BN + ReLU ----------------
// out[r][c] = relu(bn(in[r]@W[:,c] + b[c])). 64-row tile in LDS, 8x4 micro-tile.
// In-place (out==in) is safe: tile staged to LDS before any write; row-wise dep only.

__global__ __launch_bounds__(256)
void gemm_bn_relu(const float* __restrict__ in, float* __restrict__ out,
                  const float* __restrict__ W, const float* __restrict__ b,
                  const float* __restrict__ bng, const float* __restrict__ bnb,
                  const float* __restrict__ bnm, const float* __restrict__ bnv,
                  int nrows) {
    __shared__ float As[TM * DIM];
    int t = threadIdx.x;
    int r0 = blockIdx.x * TM;
    for (int i = t; i < TM * DIM; i += 256) {
        int r = r0 + (i >> 7);
        As[i] = (r < nrows) ? in[r * DIM + (i & (DIM - 1))] : 0.0f;
    }
    __syncthreads();
    int rg = t >> 5;       // 0..7
    int cg = t & 31;       // 0..31
    int c0 = cg * 4;
    float acc[8][4];
    #pragma unroll
    for (int i = 0; i < 8; ++i)
        #pragma unroll
        for (int j = 0; j < 4; ++j) acc[i][j] = 0.f;

    for (int k = 0; k < DIM; ++k) {
        float4 w4 = *reinterpret_cast<const float4*>(W + k * DIM + c0);
        #pragma unroll
        for (int i = 0; i < 8; ++i) {
            float a = As[(rg * 8 + i) * DIM + k];
            acc[i][0] += a * w4.x;
            acc[i][1] += a * w4.y;
            acc[i][2] += a * w4.z;
            acc[i][3] += a * w4.w;
        }
    }
    float4 bb = *reinterpret_cast<const float4*>(b + c0);
    float4 g4 = *reinterpret_cast<const float4*>(bng + c0);
    float4 be4 = *reinterpret_cast<const float4*>(bnb + c0);
    float4 m4 = *reinterpret_cast<const float4*>(bnm + c0);
    float4 v4 = *reinterpret_cast<const float4*>(bnv + c0);
    float bbv[4] = {bb.x, bb.y, bb.z, bb.w};
    float gv[4]  = {g4.x, g4.y, g4.z, g4.w};
    float bev[4] = {be4.x, be4.y, be4.z, be4.w};
    float mv[4]  = {m4.x, m4.y, m4.z, m4.w};
    float vv[4]  = {v4.x, v4.y, v4.z, v4.w};
    float sc[4], sh[4];
    #pragma unroll
    for (int j = 0; j < 4; ++j) {
        float s = gv[j] * rsqrtf(vv[j] + BN_EPS);
        sc[j] = s;
        sh[j] = bev[j] - mv[j] * s;
    }
    #pragma unroll
    for (int i = 0; i < 8; ++i) {
        int r = r0 + rg * 8 + i;
        if (r < nrows) {
            float4 o;
            float hv;
            hv  = (acc[i][0] + bbv[0]) * sc[0] + sh[0]; o.x = fmaxf(hv, 0.f);
            hv  = (acc[i][1] + bbv[1]) * sc[1] + sh[1]; o.y = fmaxf(hv, 0.f);
            hv  = (acc[i][2] + bbv[2]) * sc[2] + sh[2]; o.z = fmaxf(hv, 0.f);
            hv  = (acc[i][3] + bbv[3]) * sc[3] + sh[3]; o.w = fmaxf(hv, 0.f);
            *reinterpret_cast<float4*>(out + r * DIM + c0) = o;
        }
    }
}

// ---------------- global mean pool (batch is sorted) ----------------

__global__ __launch_bounds__(128)
void pool_kernel(const float* __restrict__ x, const int* __restrict__ batch,
                 float* __restrict__ g) {
    __shared__ int s_lo, s_hi;
    int gid = blockIdx.x;
    int d = threadIdx.x;
    if (d == 0) {
        int lo = 0, hi = N_NODES;
        while (lo < hi) { int mid = (lo + hi) >> 1; if (batch[mid] < gid) lo = mid + 1; else hi = mid; }
        s_lo = lo;
        lo = 0; hi = N_NODES;
        while (lo < hi) { int mid = (lo + hi) >> 1; if (batch[mid] < gid + 1) lo = mid + 1; else hi = mid; }
        s_hi = lo;
    }
    __syncthreads();
    int lo = s_lo, hi = s_hi;
    float acc = 0.f;
    for (int n = lo; n < hi; ++n) acc += x[n * DIM + d];
    float cnt = fmaxf((float)(hi - lo), 1.0f);
    g[gid * DIM + d] = acc / cnt;
}

// ---------------- head ----------------

__global__ __launch_bounds__(128)
void head1_kernel(const float* __restrict__ g, const float* __restrict__ W1,
                  const float* __restrict__ b1, float* __restrict__ h1) {
    __shared__ float gs[DIM];
    int gid = blockIdx.x, c = threadIdx.x;
    gs[c] = g[gid * DIM + c];
    __syncthreads();
    float acc = b1[c];
    for (int k = 0; k < DIM; ++k) acc += gs[k] * W1[k * DIM + c];
    h1[gid * DIM + c] = fmaxf(acc, 0.f);
}

__global__ __launch_bounds__(64)
void head2_kernel(const float* __restrict__ h1, const float* __restrict__ W2,
                  const float* __restrict__ b2, float* __restrict__ out) {
    __shared__ float hs[DIM];
    int gid = blockIdx.x;
    int t = threadIdx.x;
    hs[t] = h1[gid * DIM + t];
    hs[t + 64] = h1[gid * DIM + t + 64];
    __syncthreads();
    if (t < NCLASS) {
        float acc = b2[t];
        for (int k = 0; k < DIM; ++k) acc += hs[k] * W2[k * NCLASS + t];
        out[gid * NCLASS + t] = acc;
    }
}

// ---------------- launch ----------------

extern "C" void kernel_launch(void* const* d_in, const int* in_sizes, int n_in,
                              void* d_out, int out_size, void* d_ws, size_t ws_size,
                              hipStream_t stream) {
    const float* edge_attr = (const float*)d_in[0];
    const int*   edge_index = (const int*)d_in[1];
    const int*   batch = (const int*)d_in[2];
    const float* node_emb = (const float*)d_in[3];
    const float* edge_W = (const float*)d_in[4];
    const float* edge_b = (const float*)d_in[5];
    const float* mlp_W1 = (const float*)d_in[6];
    const float* mlp_b1 = (const float*)d_in[7];
    const float* bn1_g = (const float*)d_in[8];
    const float* bn1_b = (const float*)d_in[9];
    const float* bn1_m = (const float*)d_in[10];
    const float* bn1_v = (const float*)d_in[11];
    const float* mlp_W2 = (const float*)d_in[12];
    const float* mlp_b2 = (const float*)d_in[13];
    const float* bn2_g = (const float*)d_in[14];
    const float* bn2_b = (const float*)d_in[15];
    const float* bn2_m = (const float*)d_in[16];
    const float* bn2_v = (const float*)d_in[17];
    const float* head_W1 = (const float*)d_in[18];
    const float* head_b1 = (const float*)d_in[19];
    const float* head_W2 = (const float*)d_in[20];
    const float* head_b2 = (const float*)d_in[21];
    float* out = (float*)d_out;

    const int* src = edge_index;            // edge_index[0]
    const int* dst = edge_index + N_EDGES;  // edge_index[1]

    // carve workspace
    size_t off = 0;
    auto carve = [&](size_t bytes) {
        void* p = (char*)d_ws + off;
        off += (bytes + 255) & ~(size_t)255;
        return p;
    };
    float* x      = (float*)carve((size_t)N_NODES * DIM * 4);
    float* h      = (float*)carve((size_t)N_NODES * DIM * 4);
    int* deg      = (int*)carve((size_t)N_NODES * 4);          // reused as cursor
    int* row_off  = (int*)carve((size_t)(N_NODES + 1) * 4);
    int* csr      = (int*)carve((size_t)N_EDGES * 4);
    float* gbuf   = (float*)carve((size_t)N_GRAPHS * DIM * 4);
    float* h1buf  = (float*)carve((size_t)N_GRAPHS * DIM * 4);
    (void)ws_size;

    // CSR build
    zero_ints<<<(N_NODES + 255) / 256, 256, 0, stream>>>(deg, N_NODES);
    hist_kernel<<<(N_EDGES + 255) / 256, 256, 0, stream>>>(dst, deg);
    scan_kernel<<<1, 1024, 0, stream>>>(deg, row_off);
    zero_ints<<<(N_NODES + 255) / 256, 256, 0, stream>>>(deg, N_NODES);
    fill_csr<<<(N_EDGES + 255) / 256, 256, 0, stream>>>(dst, row_off, deg, csr);

    // x = broadcast(node_emb[0])
    init_x<<<(N_NODES * DIM + 255) / 256, 256, 0, stream>>>(x, node_emb);

    const int gemm_blocks = (N_NODES + TM - 1) / TM;
    for (int l = 0; l < LAYERS; ++l) {
        aggregate<<<N_NODES, 128, 0, stream>>>(
            x, h, edge_attr, src, csr, row_off,
            edge_W + (size_t)l * EDIM * DIM, edge_b + (size_t)l * DIM);
        gemm_bn_relu<<<gemm_blocks, 256, 0, stream>>>(
            h, h,
            mlp_W1 + (size_t)l * DIM * DIM, mlp_b1 + (size_t)l * DIM,
            bn1_g + (size_t)l * DIM, bn1_b + (size_t)l * DIM,
            bn1_m + (size_t)l * DIM, bn1_v + (size_t)l * DIM, N_NODES);
        gemm_bn_relu<<<gemm_blocks, 256, 0, stream>>>(
            h, x,
            mlp_W2 + (size_t)l * DIM * DIM, mlp_b2 + (size_t)l * DIM,
            bn2_g + (size_t)l * DIM, bn2_b + (size_t)l * DIM,
            bn2_m + (size_t)l * DIM, bn2_v + (size_t)l * DIM, N_NODES);
    }

    pool_kernel<<<N_GRAPHS, 128, 0, stream>>>(x, batch, gbuf);
    head1_kernel<<<N_GRAPHS, 128, 0, stream>>>(gbuf, head_W1, head_b1, h1buf);
    head2_kernel<<<N_GRAPHS, 64, 0, stream>>>(h1buf, head_W2, head_b2, out);
}

// Round 2
// 1143.103 us; speedup vs baseline: 1.2640x; 1.2640x over previous
//
#include <hip/hip_runtime.h>
#include <hip/hip_bf16.h>

#define N_NODES 50000
#define N_PAD   50048   // padded row count (multiple of 64) — pad rows hold garbage, never read
#define N_EDGES 800000
#define N_GRAPHS 500
#define DIM 128
#define EDIM 7
#define LAYERS 5
#define NCLASS 10
#define BN_EPS 1e-5f
#define TM 64   // rows per GEMM block
#define KC 32   // k-chunk staged in LDS

// ---------------- CSR build ----------------

__global__ void zero_ints(int* __restrict__ p, int n) {
    int i = blockIdx.x * 256 + threadIdx.x;
    if (i < n) p[i] = 0;
}

__global__ void hist_kernel(const int* __restrict__ dst, int* __restrict__ deg) {
    int e = blockIdx.x * 256 + threadIdx.x;
    if (e < N_EDGES) atomicAdd(&deg[dst[e]], 1);
}

// single-block exclusive scan over N_NODES, wave-shuffle based
__global__ void scan_kernel(const int* __restrict__ deg, int* __restrict__ row_off) {
    __shared__ int wsum[16];
    __shared__ int carry;
    int t = threadIdx.x;
    int lane = t & 63, wid = t >> 6;
    if (t == 0) carry = 0;
    __syncthreads();
    for (int base = 0; base < N_NODES; base += 1024) {
        int i = base + t;
        int v = (i < N_NODES) ? deg[i] : 0;
        int s = v;
        #pragma unroll
        for (int off = 1; off < 64; off <<= 1) {
            int u = __shfl_up(s, off, 64);
            if (lane >= off) s += u;
        }
        if (lane == 63) wsum[wid] = s;
        __syncthreads();
        if (wid == 0) {
            int ws = (lane < 16) ? wsum[lane] : 0;
            int ss = ws;
            #pragma unroll
            for (int off2 = 1; off2 < 16; off2 <<= 1) {
                int u = __shfl_up(ss, off2, 64);
                if (lane >= off2) ss += u;
            }
            if (lane < 16) wsum[lane] = ss - ws;
        }
        __syncthreads();
        int incl = s + wsum[wid];
        int excl = incl - v;
        if (i < N_NODES) row_off[i] = carry + excl;
        __syncthreads();
        if (t == 1023) carry += incl;
        __syncthreads();
    }
    if (t == 0) row_off[N_NODES] = carry;
}

__global__ void fill_csr(const int* __restrict__ dst, const int* __restrict__ row_off,
                         int* __restrict__ cursor, int* __restrict__ csr_edges) {
    int e = blockIdx.x * 256 + threadIdx.x;
    if (e < N_EDGES) {
        int d = dst[e];
        int pos = atomicAdd(&cursor[d], 1);
        csr_edges[row_off[d] + pos] = e;
    }
}

// ---------------- node init ----------------

__global__ void init_x(float* __restrict__ x, const float* __restrict__ emb) {
    int i = blockIdx.x * 256 + threadIdx.x;  // float4 index
    if (i < N_NODES * (DIM / 4)) {
        float4 v = reinterpret_cast<const float4*>(emb)[i & (DIM / 4 - 1)];
        reinterpret_cast<float4*>(x)[i] = v;
    }
}

// ---------------- aggregation (GINEConv message+sum, fused edge linear) ----------------
// 8 nodes per 256-block; 32 lanes per node, lane owns 4 features (float4).
// Edge weights live in registers (7 float4 per thread). acc starts at x[n].

__global__ __launch_bounds__(256)
void aggregate(const float* __restrict__ x, float* __restrict__ h,
               const float* __restrict__ edge_attr,
               const int* __restrict__ src,
               const int* __restrict__ csr_edges,
               const int* __restrict__ row_off,
               const float* __restrict__ eW, const float* __restrict__ eb) {
    int t = threadIdx.x;
    int nl = t >> 5;          // node within block: 0..7
    int lane = t & 31;
    int c0 = lane * 4;
    int n = blockIdx.x * 8 + nl;

    float4 Wr[EDIM];
    #pragma unroll
    for (int k = 0; k < EDIM; ++k)
        Wr[k] = *reinterpret_cast<const float4*>(eW + k * DIM + c0);
    float4 bd = *reinterpret_cast<const float4*>(eb + c0);

    float4 acc = *reinterpret_cast<const float4*>(x + (size_t)n * DIM + c0);

    int beg = row_off[n], end = row_off[n + 1];
    if (beg < end) {
        int e = csr_edges[beg];
        int s = src[e];
        for (int idx = beg; idx < end; ++idx) {
            // prefetch next edge's indices to hide the csr->src->x chain
            int e_n = 0, s_n = 0;
            if (idx + 1 < end) { e_n = csr_edges[idx + 1]; s_n = src[e_n]; }
            const float* ea = edge_attr + (size_t)e * EDIM;
            float4 xv = *reinterpret_cast<const float4*>(x + (size_t)s * DIM + c0);
            float4 el = bd;
            #pragma unroll
            for (int k = 0; k < EDIM; ++k) {
                float a = ea[k];   // 32-lane broadcast load
                el.x += a * Wr[k].x; el.y += a * Wr[k].y;
                el.z += a * Wr[k].z; el.w += a * Wr[k].w;
            }
            acc.x += fmaxf(xv.x + el.x, 0.f);
            acc.y += fmaxf(xv.y + el.y, 0.f);
            acc.z += fmaxf(xv.z + el.z, 0.f);
            acc.w += fmaxf(xv.w + el.w, 0.f);
            e = e_n; s = s_n;
        }
    }
    *reinterpret_cast<float4*>(h + (size_t)n * DIM + c0) = acc;
}

// ---------------- GEMM + bias + BN + ReLU ----------------
// out[r][c] = relu(bn(in[r]@W[:,c] + b[c])). A-tile (64x128) + W k-chunk (32x128) in LDS.
// No row guards: buffers padded to N_PAD rows; pad-row garbage is never read downstream.
// In-place safe: tile staged before writes, row-block independence.

__global__ __launch_bounds__(256)
void gemm_bn_relu(const float* __restrict__ in, float* __restrict__ out,
                  const float* __restrict__ W, const float* __restrict__ b,
                  const float* __restrict__ bng, const float* __restrict__ bnb,
                  const float* __restrict__ bnm, const float* __restrict__ bnv) {
    __shared__ float As[TM * DIM];    // 32 KB
    __shared__ float Wsh[KC * DIM];   // 16 KB
    int t = threadIdx.x;
    int r0 = blockIdx.x * TM;

    // stage A: 2048 float4, 8 per thread, coalesced
    #pragma unroll
    for (int i = 0; i < 8; ++i) {
        int idx = t + i * 256;
        reinterpret_cast<float4*>(As)[idx] =
            reinterpret_cast<const float4*>(in + (size_t)r0 * DIM)[idx];
    }

    int rg = t >> 5;       // 0..7 (row group)
    int cg = t & 31;       // 0..31
    int c0 = cg * 4;
    float acc[8][4];
    #pragma unroll
    for (int i = 0; i < 8; ++i)
        #pragma unroll
        for (int j = 0; j < 4; ++j) acc[i][j] = 0.f;

    for (int kc = 0; kc < DIM; kc += KC) {
        __syncthreads();   // protect Wsh reuse (and A staging on first pass)
        #pragma unroll
        for (int i = 0; i < 4; ++i) {
            int idx = t + i * 256;
            reinterpret_cast<float4*>(Wsh)[idx] =
                reinterpret_cast<const float4*>(W + (size_t)kc * DIM)[idx];
        }
        __syncthreads();
        #pragma unroll
        for (int kk = 0; kk < KC; kk += 4) {
            float4 a4[8];
            #pragma unroll
            for (int i = 0; i < 8; ++i)
                a4[i] = *reinterpret_cast<const float4*>(&As[(rg * 8 + i) * DIM + kc + kk]);
            #pragma unroll
            for (int j = 0; j < 4; ++j) {
                float4 w4 = *reinterpret_cast<const float4*>(&Wsh[(kk + j) * DIM + c0]);
                #pragma unroll
                for (int i = 0; i < 8; ++i) {
                    float a = (j == 0) ? a4[i].x : (j == 1) ? a4[i].y : (j == 2) ? a4[i].z : a4[i].w;
                    acc[i][0] += a * w4.x;
                    acc[i][1] += a * w4.y;
                    acc[i][2] += a * w4.z;
                    acc[i][3] += a * w4.w;
                }
            }
        }
    }

    float4 bb = *reinterpret_cast<const float4*>(b + c0);
    float4 g4 = *reinterpret_cast<const float4*>(bng + c0);
    float4 be4 = *reinterpret_cast<const float4*>(bnb + c0);
    float4 m4 = *reinterpret_cast<const float4*>(bnm + c0);
    float4 v4 = *reinterpret_cast<const float4*>(bnv + c0);
    float bbv[4] = {bb.x, bb.y, bb.z, bb.w};
    float gv[4]  = {g4.x, g4.y, g4.z, g4.w};
    float bev[4] = {be4.x, be4.y, be4.z, be4.w};
    float mv[4]  = {m4.x, m4.y, m4.z, m4.w};
    float vv[4]  = {v4.x, v4.y, v4.z, v4.w};
    float sc[4], sh[4];
    #pragma unroll
    for (int j = 0; j < 4; ++j) {
        float s = gv[j] * rsqrtf(vv[j] + BN_EPS);
        sc[j] = s;
        sh[j] = bev[j] - mv[j] * s;
    }
    #pragma unroll
    for (int i = 0; i < 8; ++i) {
        int r = r0 + rg * 8 + i;
        float4 o;
        o.x = fmaxf((acc[i][0] + bbv[0]) * sc[0] + sh[0], 0.f);
        o.y = fmaxf((acc[i][1] + bbv[1]) * sc[1] + sh[1], 0.f);
        o.z = fmaxf((acc[i][2] + bbv[2]) * sc[2] + sh[2], 0.f);
        o.w = fmaxf((acc[i][3] + bbv[3]) * sc[3] + sh[3], 0.f);
        *reinterpret_cast<float4*>(out + (size_t)r * DIM + c0) = o;
    }
}

// ---------------- global mean pool (batch is sorted) ----------------

__global__ __launch_bounds__(128)
void pool_kernel(const float* __restrict__ x, const int* __restrict__ batch,
                 float* __restrict__ g) {
    __shared__ int s_lo, s_hi;
    int gid = blockIdx.x;
    int d = threadIdx.x;
    if (d == 0) {
        int lo = 0, hi = N_NODES;
        while (lo < hi) { int mid = (lo + hi) >> 1; if (batch[mid] < gid) lo = mid + 1; else hi = mid; }
        s_lo = lo;
        lo = 0; hi = N_NODES;
        while (lo < hi) { int mid = (lo + hi) >> 1; if (batch[mid] < gid + 1) lo = mid + 1; else hi = mid; }
        s_hi = lo;
    }
    __syncthreads();
    int lo = s_lo, hi = s_hi;
    float acc = 0.f;
    for (int n = lo; n < hi; ++n) acc += x[n * DIM + d];
    float cnt = fmaxf((float)(hi - lo), 1.0f);
    g[gid * DIM + d] = acc / cnt;
}

// ---------------- head ----------------

__global__ __launch_bounds__(128)
void head1_kernel(const float* __restrict__ g, const float* __restrict__ W1,
                  const float* __restrict__ b1, float* __restrict__ h1) {
    __shared__ float gs[DIM];
    int gid = blockIdx.x, c = threadIdx.x;
    gs[c] = g[gid * DIM + c];
    __syncthreads();
    float acc = b1[c];
    for (int k = 0; k < DIM; ++k) acc += gs[k] * W1[k * DIM + c];
    h1[gid * DIM + c] = fmaxf(acc, 0.f);
}

__global__ __launch_bounds__(64)
void head2_kernel(const float* __restrict__ h1, const float* __restrict__ W2,
                  const float* __restrict__ b2, float* __restrict__ out) {
    __shared__ float hs[DIM];
    int gid = blockIdx.x;
    int t = threadIdx.x;
    hs[t] = h1[gid * DIM + t];
    hs[t + 64] = h1[gid * DIM + t + 64];
    __syncthreads();
    if (t < NCLASS) {
        float acc = b2[t];
        for (int k = 0; k < DIM; ++k) acc += hs[k] * W2[k * NCLASS + t];
        out[gid * NCLASS + t] = acc;
    }
}

// ---------------- launch ----------------

extern "C" void kernel_launch(void* const* d_in, const int* in_sizes, int n_in,
                              void* d_out, int out_size, void* d_ws, size_t ws_size,
                              hipStream_t stream) {
    const float* edge_attr = (const float*)d_in[0];
    const int*   edge_index = (const int*)d_in[1];
    const int*   batch = (const int*)d_in[2];
    const float* node_emb = (const float*)d_in[3];
    const float* edge_W = (const float*)d_in[4];
    const float* edge_b = (const float*)d_in[5];
    const float* mlp_W1 = (const float*)d_in[6];
    const float* mlp_b1 = (const float*)d_in[7];
    const float* bn1_g = (const float*)d_in[8];
    const float* bn1_b = (const float*)d_in[9];
    const float* bn1_m = (const float*)d_in[10];
    const float* bn1_v = (const float*)d_in[11];
    const float* mlp_W2 = (const float*)d_in[12];
    const float* mlp_b2 = (const float*)d_in[13];
    const float* bn2_g = (const float*)d_in[14];
    const float* bn2_b = (const float*)d_in[15];
    const float* bn2_m = (const float*)d_in[16];
    const float* bn2_v = (const float*)d_in[17];
    const float* head_W1 = (const float*)d_in[18];
    const float* head_b1 = (const float*)d_in[19];
    const float* head_W2 = (const float*)d_in[20];
    const float* head_b2 = (const float*)d_in[21];
    float* out = (float*)d_out;

    const int* src = edge_index;            // edge_index[0]
    const int* dst = edge_index + N_EDGES;  // edge_index[1]

    size_t off = 0;
    auto carve = [&](size_t bytes) {
        void* p = (char*)d_ws + off;
        off += (bytes + 255) & ~(size_t)255;
        return p;
    };
    float* x      = (float*)carve((size_t)N_PAD * DIM * 4);
    float* h      = (float*)carve((size_t)N_PAD * DIM * 4);
    int* deg      = (int*)carve((size_t)N_NODES * 4);          // reused as cursor
    int* row_off  = (int*)carve((size_t)(N_NODES + 1) * 4);
    int* csr      = (int*)carve((size_t)N_EDGES * 4);
    float* gbuf   = (float*)carve((size_t)N_GRAPHS * DIM * 4);
    float* h1buf  = (float*)carve((size_t)N_GRAPHS * DIM * 4);
    (void)ws_size;

    // CSR build
    zero_ints<<<(N_NODES + 255) / 256, 256, 0, stream>>>(deg, N_NODES);
    hist_kernel<<<(N_EDGES + 255) / 256, 256, 0, stream>>>(dst, deg);
    scan_kernel<<<1, 1024, 0, stream>>>(deg, row_off);
    zero_ints<<<(N_NODES + 255) / 256, 256, 0, stream>>>(deg, N_NODES);
    fill_csr<<<(N_EDGES + 255) / 256, 256, 0, stream>>>(dst, row_off, deg, csr);

    init_x<<<(N_NODES * (DIM / 4) + 255) / 256, 256, 0, stream>>>(x, node_emb);

    const int gemm_blocks = N_PAD / TM;   // 782, no guards
    for (int l = 0; l < LAYERS; ++l) {
        aggregate<<<N_NODES / 8, 256, 0, stream>>>(
            x, h, edge_attr, src, csr, row_off,
            edge_W + (size_t)l * EDIM * DIM, edge_b + (size_t)l * DIM);
        gemm_bn_relu<<<gemm_blocks, 256, 0, stream>>>(
            h, h,
            mlp_W1 + (size_t)l * DIM * DIM, mlp_b1 + (size_t)l * DIM,
            bn1_g + (size_t)l * DIM, bn1_b + (size_t)l * DIM,
            bn1_m + (size_t)l * DIM, bn1_v + (size_t)l * DIM);
        gemm_bn_relu<<<gemm_blocks, 256, 0, stream>>>(
            h, x,
            mlp_W2 + (size_t)l * DIM * DIM, mlp_b2 + (size_t)l * DIM,
            bn2_g + (size_t)l * DIM, bn2_b + (size_t)l * DIM,
            bn2_m + (size_t)l * DIM, bn2_v + (size_t)l * DIM);
    }

    pool_kernel<<<N_GRAPHS, 128, 0, stream>>>(x, batch, gbuf);
    head1_kernel<<<N_GRAPHS, 128, 0, stream>>>(gbuf, head_W1, head_b1, h1buf);
    head2_kernel<<<N_GRAPHS, 64, 0, stream>>>(h1buf, head_W2, head_b2, out);
}

// Round 3
// 962.520 us; speedup vs baseline: 1.5011x; 1.1876x over previous
//
#include <hip/hip_runtime.h>
#include <hip/hip_bf16.h>

#define N_NODES 50000
#define N_PAD   50048   // padded row count (multiple of 64); pad rows garbage, never consumed
#define N_EDGES 800000
#define N_GRAPHS 500
#define DIM 128
#define EDIM 7
#define LAYERS 5
#define NCLASS 10
#define BN_EPS 1e-5f
#define TM 64
#define AST 264   // LDS A row stride (ushort): 128 hi + 128 lo + 8 pad -> 528 B = 33*16 (odd) conflict-free
#define WST 72    // LDS W row stride (ushort): 32 hi + 32 lo + 8 pad -> 144 B = 9*16 (odd) conflict-free

typedef __attribute__((ext_vector_type(8))) short bf16x8;
typedef __attribute__((ext_vector_type(4))) float f32x4;

__device__ __forceinline__ unsigned short f2bf(float f) {
    unsigned u = __float_as_uint(f);
    u = u + 0x7fffu + ((u >> 16) & 1u);   // RNE
    return (unsigned short)(u >> 16);
}
__device__ __forceinline__ float bf2f(unsigned short h) {
    return __uint_as_float(((unsigned)h) << 16);
}

// ---------------- CSR build ----------------

__global__ void zero_ints(int* __restrict__ p, int n) {
    int i = blockIdx.x * 256 + threadIdx.x;
    if (i < n) p[i] = 0;
}

__global__ void hist_kernel(const int* __restrict__ dst, int* __restrict__ deg) {
    int e = blockIdx.x * 256 + threadIdx.x;
    if (e < N_EDGES) atomicAdd(&deg[dst[e]], 1);
}

__global__ void scan_kernel(const int* __restrict__ deg, int* __restrict__ row_off) {
    __shared__ int wsum[16];
    __shared__ int carry;
    int t = threadIdx.x;
    int lane = t & 63, wid = t >> 6;
    if (t == 0) carry = 0;
    __syncthreads();
    for (int base = 0; base < N_NODES; base += 1024) {
        int i = base + t;
        int v = (i < N_NODES) ? deg[i] : 0;
        int s = v;
        #pragma unroll
        for (int off = 1; off < 64; off <<= 1) {
            int u = __shfl_up(s, off, 64);
            if (lane >= off) s += u;
        }
        if (lane == 63) wsum[wid] = s;
        __syncthreads();
        if (wid == 0) {
            int ws = (lane < 16) ? wsum[lane] : 0;
            int ss = ws;
            #pragma unroll
            for (int off2 = 1; off2 < 16; off2 <<= 1) {
                int u = __shfl_up(ss, off2, 64);
                if (lane >= off2) ss += u;
            }
            if (lane < 16) wsum[lane] = ss - ws;
        }
        __syncthreads();
        int incl = s + wsum[wid];
        int excl = incl - v;
        if (i < N_NODES) row_off[i] = carry + excl;
        __syncthreads();
        if (t == 1023) carry += incl;
        __syncthreads();
    }
    if (t == 0) row_off[N_NODES] = carry;
}

__global__ void fill_csr(const int* __restrict__ dst, const int* __restrict__ row_off,
                         int* __restrict__ cursor, int* __restrict__ csr_edges) {
    int e = blockIdx.x * 256 + threadIdx.x;
    if (e < N_EDGES) {
        int d = dst[e];
        int pos = atomicAdd(&cursor[d], 1);
        csr_edges[row_off[d] + pos] = e;
    }
}

// ---------------- one-time preps ----------------

__global__ void init_x(float* __restrict__ x, unsigned short* __restrict__ xb,
                       const float* __restrict__ emb) {
    int i = blockIdx.x * 256 + threadIdx.x;
    if (i < N_NODES * DIM) {
        float v = emb[i & (DIM - 1)];
        x[i] = v;
        xb[i] = f2bf(v);
    }
}

// edge_attr [E,7] fp32 -> bf16 padded [E,8]
__global__ void prep_ea(const float* __restrict__ ea, unsigned short* __restrict__ ea8) {
    int i = blockIdx.x * 256 + threadIdx.x;
    if (i < N_EDGES * 8) {
        int e = i >> 3, k = i & 7;
        float v = (k < EDIM) ? ea[e * EDIM + k] : 0.f;
        ea8[i] = f2bf(v);
    }
}

// W [k][n] fp32 -> transposed hi/lo bf16 Wt[m][n][k], m in [0,10): 5x mlp_W1 then 5x mlp_W2
__global__ void prep_w(const float* __restrict__ W1, const float* __restrict__ W2,
                       unsigned short* __restrict__ Wthi, unsigned short* __restrict__ Wtlo) {
    int i = blockIdx.x * 256 + threadIdx.x;
    if (i >= 2 * LAYERS * DIM * DIM) return;
    int m = i >> 14;
    int n = i & 127;          // fastest -> coalesced read of W[k][n]
    int k = (i >> 7) & 127;
    const float* W = (m < LAYERS) ? (W1 + (size_t)m * DIM * DIM)
                                  : (W2 + (size_t)(m - LAYERS) * DIM * DIM);
    float v = W[k * DIM + n];
    unsigned short hi = f2bf(v);
    float lo = v - bf2f(hi);
    size_t o = ((size_t)m << 14) + (size_t)n * DIM + k;   // scattered 2B stores; L2 merges lines
    Wthi[o] = hi;
    Wtlo[o] = f2bf(lo);
}

// ---------------- aggregation: bf16 gather + fused edge linear ----------------
// 8 nodes / 256-thread block; 32 lanes per node, lane owns 4 features.
// Software pipeline: next edge's (csr,src,ea,xb) issued before current compute.

__global__ __launch_bounds__(256)
void aggregate(const float* __restrict__ x, const unsigned short* __restrict__ xb,
               float* __restrict__ h,
               const unsigned short* __restrict__ ea8,
               const int* __restrict__ src,
               const int* __restrict__ csr_edges,
               const int* __restrict__ row_off,
               const float* __restrict__ eW, const float* __restrict__ eb) {
    int t = threadIdx.x;
    int nl = t >> 5;
    int lane = t & 31;
    int c0 = lane * 4;
    int n = blockIdx.x * 8 + nl;

    float4 Wr[EDIM];
    #pragma unroll
    for (int k = 0; k < EDIM; ++k)
        Wr[k] = *reinterpret_cast<const float4*>(eW + k * DIM + c0);
    float4 bd = *reinterpret_cast<const float4*>(eb + c0);
    float4 acc = *reinterpret_cast<const float4*>(x + (size_t)n * DIM + c0);

    int beg = row_off[n], end = row_off[n + 1];
    if (beg < end) {
        int e = csr_edges[beg];
        int s = src[e];
        uint4 eav = *reinterpret_cast<const uint4*>(ea8 + (size_t)e * 8);
        uint2 xv = *reinterpret_cast<const uint2*>(xb + (size_t)s * DIM + c0);
        for (int idx = beg; ; ) {
            uint4 eav1 = {};
            uint2 xv1 = {};
            bool more = (idx + 1 < end);
            if (more) {
                int e1 = csr_edges[idx + 1];
                int s1 = src[e1];
                eav1 = *reinterpret_cast<const uint4*>(ea8 + (size_t)e1 * 8);
                xv1 = *reinterpret_cast<const uint2*>(xb + (size_t)s1 * DIM + c0);
            }
            float a0 = __uint_as_float(eav.x << 16);
            float a1 = __uint_as_float(eav.x & 0xffff0000u);
            float a2 = __uint_as_float(eav.y << 16);
            float a3 = __uint_as_float(eav.y & 0xffff0000u);
            float a4 = __uint_as_float(eav.z << 16);
            float a5 = __uint_as_float(eav.z & 0xffff0000u);
            float a6 = __uint_as_float(eav.w << 16);
            float4 el = bd;
            el.x += a0*Wr[0].x; el.y += a0*Wr[0].y; el.z += a0*Wr[0].z; el.w += a0*Wr[0].w;
            el.x += a1*Wr[1].x; el.y += a1*Wr[1].y; el.z += a1*Wr[1].z; el.w += a1*Wr[1].w;
            el.x += a2*Wr[2].x; el.y += a2*Wr[2].y; el.z += a2*Wr[2].z; el.w += a2*Wr[2].w;
            el.x += a3*Wr[3].x; el.y += a3*Wr[3].y; el.z += a3*Wr[3].z; el.w += a3*Wr[3].w;
            el.x += a4*Wr[4].x; el.y += a4*Wr[4].y; el.z += a4*Wr[4].z; el.w += a4*Wr[4].w;
            el.x += a5*Wr[5].x; el.y += a5*Wr[5].y; el.z += a5*Wr[5].z; el.w += a5*Wr[5].w;
            el.x += a6*Wr[6].x; el.y += a6*Wr[6].y; el.z += a6*Wr[6].z; el.w += a6*Wr[6].w;
            acc.x += fmaxf(__uint_as_float(xv.x << 16)          + el.x, 0.f);
            acc.y += fmaxf(__uint_as_float(xv.x & 0xffff0000u)  + el.y, 0.f);
            acc.z += fmaxf(__uint_as_float(xv.y << 16)          + el.z, 0.f);
            acc.w += fmaxf(__uint_as_float(xv.y & 0xffff0000u)  + el.w, 0.f);
            if (!more) break;
            eav = eav1; xv = xv1; ++idx;
        }
    }
    *reinterpret_cast<float4*>(h + (size_t)n * DIM + c0) = acc;
}

// ---------------- MFMA GEMM (bf16 hi/lo split, fp32-class) + bias + BN + ReLU ----------------
// C = A@W: A [64x128] fp32 converted to hi/lo bf16 in LDS during stage; Wt pre-split [n][k].
// 3 MFMAs per tile: hi*hi + hi*lo + lo*hi. In-place safe (tile fully staged first).

__global__ __launch_bounds__(256)
void gemm_mfma(const float* __restrict__ in, float* __restrict__ out,
               const unsigned short* __restrict__ Wthi,
               const unsigned short* __restrict__ Wtlo,
               const float* __restrict__ b,
               const float* __restrict__ bng, const float* __restrict__ bnb,
               const float* __restrict__ bnm, const float* __restrict__ bnv,
               unsigned short* __restrict__ xb_out) {
    __shared__ __align__(16) unsigned short A2[TM * AST];   // 33792 B
    __shared__ __align__(16) unsigned short W2[DIM * WST];  // 18432 B
    int t = threadIdx.x;
    int r0 = blockIdx.x * TM;

    // stage A with hi/lo split (coalesced float4 reads)
    #pragma unroll
    for (int i = 0; i < 8; ++i) {
        int idx = t + i * 256;           // float4 index in 64x128 tile
        int row = idx >> 5;
        int kp = (idx & 31) * 4;
        float4 v = reinterpret_cast<const float4*>(in + (size_t)r0 * DIM)[idx];
        unsigned short h0 = f2bf(v.x), h1 = f2bf(v.y), h2 = f2bf(v.z), h3 = f2bf(v.w);
        ushort4 hv; hv.x = h0; hv.y = h1; hv.z = h2; hv.w = h3;
        ushort4 lv;
        lv.x = f2bf(v.x - bf2f(h0)); lv.y = f2bf(v.y - bf2f(h1));
        lv.z = f2bf(v.z - bf2f(h2)); lv.w = f2bf(v.w - bf2f(h3));
        *reinterpret_cast<ushort4*>(&A2[row * AST + kp]) = hv;
        *reinterpret_cast<ushort4*>(&A2[row * AST + 128 + kp]) = lv;
    }

    int w = t >> 6;       // wave 0..3 -> cols w*32..w*32+31
    int lane = t & 63;
    int q = lane >> 4;    // quad
    int l16 = lane & 15;

    f32x4 acc[4][2];
    #pragma unroll
    for (int mt = 0; mt < 4; ++mt)
        #pragma unroll
        for (int nt = 0; nt < 2; ++nt)
            acc[mt][nt] = (f32x4){0.f, 0.f, 0.f, 0.f};

    for (int kc = 0; kc < DIM; kc += 32) {
        __syncthreads();
        // stage W chunk [128 n][32 k] hi+lo
        {
            int n = t >> 1, half = t & 1;
            const uint4* gh = reinterpret_cast<const uint4*>(Wthi + (size_t)n * DIM + kc + half * 16);
            const uint4* gl = reinterpret_cast<const uint4*>(Wtlo + (size_t)n * DIM + kc + half * 16);
            uint4 h0 = gh[0], h1 = gh[1];
            uint4 l0 = gl[0], l1 = gl[1];
            uint4* dh = reinterpret_cast<uint4*>(&W2[n * WST + half * 16]);
            dh[0] = h0; dh[1] = h1;
            uint4* dl = reinterpret_cast<uint4*>(&W2[n * WST + 32 + half * 16]);
            dl[0] = l0; dl[1] = l1;
        }
        __syncthreads();

        bf16x8 ahi[4], alo[4], bhi[2], blo[2];
        #pragma unroll
        for (int mt = 0; mt < 4; ++mt) {
            ahi[mt] = *reinterpret_cast<const bf16x8*>(&A2[(mt * 16 + l16) * AST + kc + q * 8]);
            alo[mt] = *reinterpret_cast<const bf16x8*>(&A2[(mt * 16 + l16) * AST + 128 + kc + q * 8]);
        }
        #pragma unroll
        for (int nt = 0; nt < 2; ++nt) {
            int n = w * 32 + nt * 16 + l16;
            bhi[nt] = *reinterpret_cast<const bf16x8*>(&W2[n * WST + q * 8]);
            blo[nt] = *reinterpret_cast<const bf16x8*>(&W2[n * WST + 32 + q * 8]);
        }
        #pragma unroll
        for (int mt = 0; mt < 4; ++mt)
            #pragma unroll
            for (int nt = 0; nt < 2; ++nt) {
                acc[mt][nt] = __builtin_amdgcn_mfma_f32_16x16x32_bf16(ahi[mt], bhi[nt], acc[mt][nt], 0, 0, 0);
                acc[mt][nt] = __builtin_amdgcn_mfma_f32_16x16x32_bf16(ahi[mt], blo[nt], acc[mt][nt], 0, 0, 0);
                acc[mt][nt] = __builtin_amdgcn_mfma_f32_16x16x32_bf16(alo[mt], bhi[nt], acc[mt][nt], 0, 0, 0);
            }
    }

    // epilogue: bias + BN + ReLU; C/D layout col=lane&15, row=quad*4+reg
    #pragma unroll
    for (int nt = 0; nt < 2; ++nt) {
        int col = w * 32 + nt * 16 + l16;
        float bias = b[col];
        float sc = bng[col] * rsqrtf(bnv[col] + BN_EPS);
        float sh = bnb[col] - bnm[col] * sc;
        #pragma unroll
        for (int mt = 0; mt < 4; ++mt) {
            #pragma unroll
            for (int r = 0; r < 4; ++r) {
                int row = r0 + mt * 16 + q * 4 + r;
                float o = fmaxf((acc[mt][nt][r] + bias) * sc + sh, 0.f);
                out[(size_t)row * DIM + col] = o;
                if (xb_out) xb_out[(size_t)row * DIM + col] = f2bf(o);
            }
        }
    }
}

// ---------------- global mean pool (batch sorted) ----------------

__global__ __launch_bounds__(128)
void pool_kernel(const float* __restrict__ x, const int* __restrict__ batch,
                 float* __restrict__ g) {
    __shared__ int s_lo, s_hi;
    int gid = blockIdx.x;
    int d = threadIdx.x;
    if (d == 0) {
        int lo = 0, hi = N_NODES;
        while (lo < hi) { int mid = (lo + hi) >> 1; if (batch[mid] < gid) lo = mid + 1; else hi = mid; }
        s_lo = lo;
        lo = 0; hi = N_NODES;
        while (lo < hi) { int mid = (lo + hi) >> 1; if (batch[mid] < gid + 1) lo = mid + 1; else hi = mid; }
        s_hi = lo;
    }
    __syncthreads();
    int lo = s_lo, hi = s_hi;
    float acc = 0.f;
    for (int n = lo; n < hi; ++n) acc += x[n * DIM + d];
    float cnt = fmaxf((float)(hi - lo), 1.0f);
    g[gid * DIM + d] = acc / cnt;
}

// ---------------- head ----------------

__global__ __launch_bounds__(128)
void head1_kernel(const float* __restrict__ g, const float* __restrict__ W1,
                  const float* __restrict__ b1, float* __restrict__ h1) {
    __shared__ float gs[DIM];
    int gid = blockIdx.x, c = threadIdx.x;
    gs[c] = g[gid * DIM + c];
    __syncthreads();
    float acc = b1[c];
    for (int k = 0; k < DIM; ++k) acc += gs[k] * W1[k * DIM + c];
    h1[gid * DIM + c] = fmaxf(acc, 0.f);
}

__global__ __launch_bounds__(64)
void head2_kernel(const float* __restrict__ h1, const float* __restrict__ W2,
                  const float* __restrict__ b2, float* __restrict__ out) {
    __shared__ float hs[DIM];
    int gid = blockIdx.x;
    int t = threadIdx.x;
    hs[t] = h1[gid * DIM + t];
    hs[t + 64] = h1[gid * DIM + t + 64];
    __syncthreads();
    if (t < NCLASS) {
        float acc = b2[t];
        for (int k = 0; k < DIM; ++k) acc += hs[k] * W2[k * NCLASS + t];
        out[gid * NCLASS + t] = acc;
    }
}

// ---------------- launch ----------------

extern "C" void kernel_launch(void* const* d_in, const int* in_sizes, int n_in,
                              void* d_out, int out_size, void* d_ws, size_t ws_size,
                              hipStream_t stream) {
    const float* edge_attr = (const float*)d_in[0];
    const int*   edge_index = (const int*)d_in[1];
    const int*   batch = (const int*)d_in[2];
    const float* node_emb = (const float*)d_in[3];
    const float* edge_W = (const float*)d_in[4];
    const float* edge_b = (const float*)d_in[5];
    const float* mlp_W1 = (const float*)d_in[6];
    const float* mlp_b1 = (const float*)d_in[7];
    const float* bn1_g = (const float*)d_in[8];
    const float* bn1_b = (const float*)d_in[9];
    const float* bn1_m = (const float*)d_in[10];
    const float* bn1_v = (const float*)d_in[11];
    const float* mlp_W2 = (const float*)d_in[12];
    const float* mlp_b2 = (const float*)d_in[13];
    const float* bn2_g = (const float*)d_in[14];
    const float* bn2_b = (const float*)d_in[15];
    const float* bn2_m = (const float*)d_in[16];
    const float* bn2_v = (const float*)d_in[17];
    const float* head_W1 = (const float*)d_in[18];
    const float* head_b1 = (const float*)d_in[19];
    const float* head_W2 = (const float*)d_in[20];
    const float* head_b2 = (const float*)d_in[21];
    float* out = (float*)d_out;

    const int* src = edge_index;
    const int* dst = edge_index + N_EDGES;

    size_t off = 0;
    auto carve = [&](size_t bytes) {
        void* p = (char*)d_ws + off;
        off += (bytes + 255) & ~(size_t)255;
        return p;
    };
    float* x            = (float*)carve((size_t)N_PAD * DIM * 4);
    unsigned short* xb  = (unsigned short*)carve((size_t)N_PAD * DIM * 2);
    float* h            = (float*)carve((size_t)N_PAD * DIM * 4);
    unsigned short* ea8 = (unsigned short*)carve((size_t)N_EDGES * 8 * 2);
    unsigned short* Wthi = (unsigned short*)carve((size_t)2 * LAYERS * DIM * DIM * 2);
    unsigned short* Wtlo = (unsigned short*)carve((size_t)2 * LAYERS * DIM * DIM * 2);
    int* deg      = (int*)carve((size_t)N_NODES * 4);
    int* row_off  = (int*)carve((size_t)(N_NODES + 1) * 4);
    int* csr      = (int*)carve((size_t)N_EDGES * 4);
    float* gbuf   = (float*)carve((size_t)N_GRAPHS * DIM * 4);
    float* h1buf  = (float*)carve((size_t)N_GRAPHS * DIM * 4);
    (void)ws_size;

    // CSR build + one-time preps
    zero_ints<<<(N_NODES + 255) / 256, 256, 0, stream>>>(deg, N_NODES);
    hist_kernel<<<(N_EDGES + 255) / 256, 256, 0, stream>>>(dst, deg);
    scan_kernel<<<1, 1024, 0, stream>>>(deg, row_off);
    zero_ints<<<(N_NODES + 255) / 256, 256, 0, stream>>>(deg, N_NODES);
    fill_csr<<<(N_EDGES + 255) / 256, 256, 0, stream>>>(dst, row_off, deg, csr);

    init_x<<<(N_NODES * DIM + 255) / 256, 256, 0, stream>>>(x, xb, node_emb);
    prep_ea<<<(N_EDGES * 8 + 255) / 256, 256, 0, stream>>>(edge_attr, ea8);
    prep_w<<<(2 * LAYERS * DIM * DIM + 255) / 256, 256, 0, stream>>>(mlp_W1, mlp_W2, Wthi, Wtlo);

    const int gemm_blocks = N_PAD / TM;   // 782
    for (int l = 0; l < LAYERS; ++l) {
        aggregate<<<N_NODES / 8, 256, 0, stream>>>(
            x, xb, h, ea8, src, csr, row_off,
            edge_W + (size_t)l * EDIM * DIM, edge_b + (size_t)l * DIM);
        gemm_mfma<<<gemm_blocks, 256, 0, stream>>>(
            h, h,
            Wthi + ((size_t)l << 14), Wtlo + ((size_t)l << 14),
            mlp_b1 + (size_t)l * DIM,
            bn1_g + (size_t)l * DIM, bn1_b + (size_t)l * DIM,
            bn1_m + (size_t)l * DIM, bn1_v + (size_t)l * DIM,
            nullptr);
        gemm_mfma<<<gemm_blocks, 256, 0, stream>>>(
            h, x,
            Wthi + ((size_t)(LAYERS + l) << 14), Wtlo + ((size_t)(LAYERS + l) << 14),
            mlp_b2 + (size_t)l * DIM,
            bn2_g + (size_t)l * DIM, bn2_b + (size_t)l * DIM,
            bn2_m + (size_t)l * DIM, bn2_v + (size_t)l * DIM,
            xb);
    }

    pool_kernel<<<N_GRAPHS, 128, 0, stream>>>(x, batch, gbuf);
    head1_kernel<<<N_GRAPHS, 128, 0, stream>>>(gbuf, head_W1, head_b1, h1buf);
    head2_kernel<<<N_GRAPHS, 64, 0, stream>>>(h1buf, head_W2, head_b2, out);
}

// Round 4
// 935.705 us; speedup vs baseline: 1.5441x; 1.0287x over previous
//
#include <hip/hip_runtime.h>
#include <hip/hip_bf16.h>

#define N_NODES 50000
#define N_PAD   50048   // padded row count (multiple of 64); pad rows garbage, never consumed
#define N_EDGES 800000
#define N_GRAPHS 500
#define DIM 128
#define EDIM 7
#define LAYERS 5
#define NCLASS 10
#define BN_EPS 1e-5f
#define TM 64
#define AST 264     // LDS A row stride (ushort): 528 B = 33*16 (odd 16B multiple) -> conflict-free b128
#define NB 16       // nodes per aggregate block
#define ECAP 2048   // staged edges per aggregate block (block avg ~256; overflow -> global fallback)

typedef __attribute__((ext_vector_type(8))) short bf16x8;
typedef __attribute__((ext_vector_type(4))) float f32x4;

__device__ __forceinline__ unsigned short f2bf(float f) {
    unsigned u = __float_as_uint(f);
    u = u + 0x7fffu + ((u >> 16) & 1u);   // RNE
    return (unsigned short)(u >> 16);
}
__device__ __forceinline__ float bf2f(unsigned short h) {
    return __uint_as_float(((unsigned)h) << 16);
}

// ---------------- CSR build ----------------

__global__ void zero_ints(int* __restrict__ p, int n) {
    int i = blockIdx.x * 256 + threadIdx.x;
    if (i < n) p[i] = 0;
}

__global__ void hist_kernel(const int* __restrict__ dst, int* __restrict__ deg) {
    int e = blockIdx.x * 256 + threadIdx.x;
    if (e < N_EDGES) atomicAdd(&deg[dst[e]], 1);
}

__global__ void scan_kernel(const int* __restrict__ deg, int* __restrict__ row_off) {
    __shared__ int wsum[16];
    __shared__ int carry;
    int t = threadIdx.x;
    int lane = t & 63, wid = t >> 6;
    if (t == 0) carry = 0;
    __syncthreads();
    for (int base = 0; base < N_NODES; base += 1024) {
        int i = base + t;
        int v = (i < N_NODES) ? deg[i] : 0;
        int s = v;
        #pragma unroll
        for (int off = 1; off < 64; off <<= 1) {
            int u = __shfl_up(s, off, 64);
            if (lane >= off) s += u;
        }
        if (lane == 63) wsum[wid] = s;
        __syncthreads();
        if (wid == 0) {
            int ws = (lane < 16) ? wsum[lane] : 0;
            int ss = ws;
            #pragma unroll
            for (int off2 = 1; off2 < 16; off2 <<= 1) {
                int u = __shfl_up(ss, off2, 64);
                if (lane >= off2) ss += u;
            }
            if (lane < 16) wsum[lane] = ss - ws;
        }
        __syncthreads();
        int incl = s + wsum[wid];
        int excl = incl - v;
        if (i < N_NODES) row_off[i] = carry + excl;
        __syncthreads();
        if (t == 1023) carry += incl;
        __syncthreads();
    }
    if (t == 0) row_off[N_NODES] = carry;
}

__global__ void fill_csr(const int* __restrict__ dst, const int* __restrict__ row_off,
                         int* __restrict__ cursor, int* __restrict__ csr_edges) {
    int e = blockIdx.x * 256 + threadIdx.x;
    if (e < N_EDGES) {
        int d = dst[e];
        int pos = atomicAdd(&cursor[d], 1);
        csr_edges[row_off[d] + pos] = e;
    }
}

// ---------------- one-time preps ----------------

__global__ void init_x(float* __restrict__ x, unsigned short* __restrict__ xb,
                       const float* __restrict__ emb) {
    int i = blockIdx.x * 256 + threadIdx.x;
    if (i < N_NODES * DIM) {
        float v = emb[i & (DIM - 1)];
        x[i] = v;
        xb[i] = f2bf(v);
    }
}

__global__ void prep_ea(const float* __restrict__ ea, unsigned short* __restrict__ ea8) {
    int i = blockIdx.x * 256 + threadIdx.x;
    if (i < N_EDGES * 8) {
        int e = i >> 3, k = i & 7;
        float v = (k < EDIM) ? ea[e * EDIM + k] : 0.f;
        ea8[i] = f2bf(v);
    }
}

// W [k][n] fp32 -> transposed hi/lo bf16 Wt[m][n][k]
__global__ void prep_w(const float* __restrict__ W1, const float* __restrict__ W2,
                       unsigned short* __restrict__ Wthi, unsigned short* __restrict__ Wtlo) {
    int i = blockIdx.x * 256 + threadIdx.x;
    if (i >= 2 * LAYERS * DIM * DIM) return;
    int m = i >> 14;
    int n = i & 127;
    int k = (i >> 7) & 127;
    const float* W = (m < LAYERS) ? (W1 + (size_t)m * DIM * DIM)
                                  : (W2 + (size_t)(m - LAYERS) * DIM * DIM);
    float v = W[k * DIM + n];
    unsigned short hi = f2bf(v);
    float lo = v - bf2f(hi);
    size_t o = ((size_t)m << 14) + (size_t)n * DIM + k;
    Wthi[o] = hi;
    Wtlo[o] = f2bf(lo);
}

// ---------------- aggregation ----------------
// NB=16 nodes / 256-thread block; 16 lanes per node, lane owns 8 features.
// Block's (edge, src) pairs staged in LDS (coalesced) to kill per-edge index chains.

__global__ __launch_bounds__(256)
void aggregate(const float* __restrict__ x, const unsigned short* __restrict__ xb,
               float* __restrict__ h,
               const unsigned short* __restrict__ ea8,
               const int* __restrict__ srcArr,
               const int* __restrict__ csr_edges,
               const int* __restrict__ row_off,
               const float* __restrict__ eW, const float* __restrict__ eb) {
    __shared__ int2 es[ECAP];
    int t = threadIdx.x;
    int n0 = blockIdx.x * NB;
    int ebeg = row_off[n0];
    int eend = row_off[n0 + NB];
    int ne = eend - ebeg;
    for (int i = t; i < ne && i < ECAP; i += 256) {
        int e = csr_edges[ebeg + i];
        es[i] = make_int2(e, srcArr[e]);
    }
    __syncthreads();

    int nl = t >> 4;
    int l = t & 15;
    int c0 = l * 8;
    int n = n0 + nl;

    float4 W0[EDIM], W1v[EDIM];
    #pragma unroll
    for (int k = 0; k < EDIM; ++k) {
        W0[k]  = *reinterpret_cast<const float4*>(eW + k * DIM + c0);
        W1v[k] = *reinterpret_cast<const float4*>(eW + k * DIM + c0 + 4);
    }
    float4 b0 = *reinterpret_cast<const float4*>(eb + c0);
    float4 b1 = *reinterpret_cast<const float4*>(eb + c0 + 4);
    float4 acc0 = *reinterpret_cast<const float4*>(x + (size_t)n * DIM + c0);
    float4 acc1 = *reinterpret_cast<const float4*>(x + (size_t)n * DIM + c0 + 4);

    int beg = row_off[n], end = row_off[n + 1];
    if (beg < end) {
        // load first edge
        int rel = beg - ebeg;
        int e, s;
        if (rel < ECAP) { int2 p = es[rel]; e = p.x; s = p.y; }
        else { e = csr_edges[beg]; s = srcArr[e]; }
        uint4 eav = *reinterpret_cast<const uint4*>(ea8 + (size_t)e * 8);
        uint4 xv  = *reinterpret_cast<const uint4*>(xb + (size_t)s * DIM + c0);
        for (int idx = beg; ; ) {
            bool more = (idx + 1 < end);
            uint4 eav1 = {}, xv1 = {};
            if (more) {
                int rel1 = idx + 1 - ebeg;
                int e1, s1;
                if (rel1 < ECAP) { int2 p = es[rel1]; e1 = p.x; s1 = p.y; }
                else { e1 = csr_edges[idx + 1]; s1 = srcArr[e1]; }
                eav1 = *reinterpret_cast<const uint4*>(ea8 + (size_t)e1 * 8);
                xv1  = *reinterpret_cast<const uint4*>(xb + (size_t)s1 * DIM + c0);
            }
            float a0 = __uint_as_float(eav.x << 16);
            float a1 = __uint_as_float(eav.x & 0xffff0000u);
            float a2 = __uint_as_float(eav.y << 16);
            float a3 = __uint_as_float(eav.y & 0xffff0000u);
            float a4 = __uint_as_float(eav.z << 16);
            float a5 = __uint_as_float(eav.z & 0xffff0000u);
            float a6 = __uint_as_float(eav.w << 16);
            float4 el0 = b0, el1 = b1;
            el0.x += a0*W0[0].x; el0.y += a0*W0[0].y; el0.z += a0*W0[0].z; el0.w += a0*W0[0].w;
            el1.x += a0*W1v[0].x; el1.y += a0*W1v[0].y; el1.z += a0*W1v[0].z; el1.w += a0*W1v[0].w;
            el0.x += a1*W0[1].x; el0.y += a1*W0[1].y; el0.z += a1*W0[1].z; el0.w += a1*W0[1].w;
            el1.x += a1*W1v[1].x; el1.y += a1*W1v[1].y; el1.z += a1*W1v[1].z; el1.w += a1*W1v[1].w;
            el0.x += a2*W0[2].x; el0.y += a2*W0[2].y; el0.z += a2*W0[2].z; el0.w += a2*W0[2].w;
            el1.x += a2*W1v[2].x; el1.y += a2*W1v[2].y; el1.z += a2*W1v[2].z; el1.w += a2*W1v[2].w;
            el0.x += a3*W0[3].x; el0.y += a3*W0[3].y; el0.z += a3*W0[3].z; el0.w += a3*W0[3].w;
            el1.x += a3*W1v[3].x; el1.y += a3*W1v[3].y; el1.z += a3*W1v[3].z; el1.w += a3*W1v[3].w;
            el0.x += a4*W0[4].x; el0.y += a4*W0[4].y; el0.z += a4*W0[4].z; el0.w += a4*W0[4].w;
            el1.x += a4*W1v[4].x; el1.y += a4*W1v[4].y; el1.z += a4*W1v[4].z; el1.w += a4*W1v[4].w;
            el0.x += a5*W0[5].x; el0.y += a5*W0[5].y; el0.z += a5*W0[5].z; el0.w += a5*W0[5].w;
            el1.x += a5*W1v[5].x; el1.y += a5*W1v[5].y; el1.z += a5*W1v[5].z; el1.w += a5*W1v[5].w;
            el0.x += a6*W0[6].x; el0.y += a6*W0[6].y; el0.z += a6*W0[6].z; el0.w += a6*W0[6].w;
            el1.x += a6*W1v[6].x; el1.y += a6*W1v[6].y; el1.z += a6*W1v[6].z; el1.w += a6*W1v[6].w;
            acc0.x += fmaxf(__uint_as_float(xv.x << 16)         + el0.x, 0.f);
            acc0.y += fmaxf(__uint_as_float(xv.x & 0xffff0000u) + el0.y, 0.f);
            acc0.z += fmaxf(__uint_as_float(xv.y << 16)         + el0.z, 0.f);
            acc0.w += fmaxf(__uint_as_float(xv.y & 0xffff0000u) + el0.w, 0.f);
            acc1.x += fmaxf(__uint_as_float(xv.z << 16)         + el1.x, 0.f);
            acc1.y += fmaxf(__uint_as_float(xv.z & 0xffff0000u) + el1.y, 0.f);
            acc1.z += fmaxf(__uint_as_float(xv.w << 16)         + el1.z, 0.f);
            acc1.w += fmaxf(__uint_as_float(xv.w & 0xffff0000u) + el1.w, 0.f);
            if (!more) break;
            eav = eav1; xv = xv1; ++idx;
        }
    }
    *reinterpret_cast<float4*>(h + (size_t)n * DIM + c0) = acc0;
    *reinterpret_cast<float4*>(h + (size_t)n * DIM + c0 + 4) = acc1;
}

// ---------------- MFMA GEMM (hi/lo bf16 split) + bias + BN + ReLU ----------------
// B fragments (32 cols/wave, all K, hi+lo) in REGISTERS, loaded at entry while A stages.
// A staged in LDS once with hi/lo split; ONE barrier; K-loop is pure LDS+MFMA.

__global__ __launch_bounds__(256)
void gemm_mfma(const float* __restrict__ in, float* __restrict__ out,
               const unsigned short* __restrict__ Wthi,
               const unsigned short* __restrict__ Wtlo,
               const float* __restrict__ b,
               const float* __restrict__ bng, const float* __restrict__ bnb,
               const float* __restrict__ bnm, const float* __restrict__ bnv,
               unsigned short* __restrict__ xb_out) {
    __shared__ __align__(16) unsigned short A2[TM * AST];   // 33792 B
    int t = threadIdx.x;
    int r0 = blockIdx.x * TM;
    int w = t >> 6;
    int lane = t & 63;
    int q = lane >> 4;
    int l16 = lane & 15;

    // B register fragments: n = w*32 + nt*16 + l16, k-contiguous rows of Wt
    bf16x8 bhi[2][4], blo[2][4];
    #pragma unroll
    for (int nt = 0; nt < 2; ++nt) {
        int n = w * 32 + nt * 16 + l16;
        const bf16x8* gh = reinterpret_cast<const bf16x8*>(Wthi + (size_t)n * DIM);
        const bf16x8* gl = reinterpret_cast<const bf16x8*>(Wtlo + (size_t)n * DIM);
        #pragma unroll
        for (int kc = 0; kc < 4; ++kc) {
            bhi[nt][kc] = gh[kc * 4 + q];
            blo[nt][kc] = gl[kc * 4 + q];
        }
    }

    // stage A with hi/lo split (coalesced float4 reads)
    #pragma unroll
    for (int i = 0; i < 8; ++i) {
        int idx = t + i * 256;           // float4 index in 64x128 tile
        int row = idx >> 5;
        int kp = (idx & 31) * 4;
        float4 v = reinterpret_cast<const float4*>(in + (size_t)r0 * DIM)[idx];
        unsigned short h0 = f2bf(v.x), h1 = f2bf(v.y), h2 = f2bf(v.z), h3 = f2bf(v.w);
        ushort4 hv; hv.x = h0; hv.y = h1; hv.z = h2; hv.w = h3;
        ushort4 lv;
        lv.x = f2bf(v.x - bf2f(h0)); lv.y = f2bf(v.y - bf2f(h1));
        lv.z = f2bf(v.z - bf2f(h2)); lv.w = f2bf(v.w - bf2f(h3));
        *reinterpret_cast<ushort4*>(&A2[row * AST + kp]) = hv;
        *reinterpret_cast<ushort4*>(&A2[row * AST + 128 + kp]) = lv;
    }
    __syncthreads();   // the only barrier

    f32x4 acc[4][2];
    #pragma unroll
    for (int mt = 0; mt < 4; ++mt)
        #pragma unroll
        for (int nt = 0; nt < 2; ++nt)
            acc[mt][nt] = (f32x4){0.f, 0.f, 0.f, 0.f};

    #pragma unroll
    for (int kc = 0; kc < 4; ++kc) {
        bf16x8 ahi[4], alo[4];
        #pragma unroll
        for (int mt = 0; mt < 4; ++mt) {
            ahi[mt] = *reinterpret_cast<const bf16x8*>(&A2[(mt * 16 + l16) * AST + kc * 32 + q * 8]);
            alo[mt] = *reinterpret_cast<const bf16x8*>(&A2[(mt * 16 + l16) * AST + 128 + kc * 32 + q * 8]);
        }
        #pragma unroll
        for (int mt = 0; mt < 4; ++mt)
            #pragma unroll
            for (int nt = 0; nt < 2; ++nt) {
                acc[mt][nt] = __builtin_amdgcn_mfma_f32_16x16x32_bf16(ahi[mt], bhi[nt][kc], acc[mt][nt], 0, 0, 0);
                acc[mt][nt] = __builtin_amdgcn_mfma_f32_16x16x32_bf16(ahi[mt], blo[nt][kc], acc[mt][nt], 0, 0, 0);
                acc[mt][nt] = __builtin_amdgcn_mfma_f32_16x16x32_bf16(alo[mt], bhi[nt][kc], acc[mt][nt], 0, 0, 0);
            }
    }

    // epilogue: bias + BN + ReLU; C/D layout col=lane&15, row=quad*4+reg
    #pragma unroll
    for (int nt = 0; nt < 2; ++nt) {
        int col = w * 32 + nt * 16 + l16;
        float bias = b[col];
        float sc = bng[col] * rsqrtf(bnv[col] + BN_EPS);
        float sh = bnb[col] - bnm[col] * sc;
        #pragma unroll
        for (int mt = 0; mt < 4; ++mt) {
            #pragma unroll
            for (int r = 0; r < 4; ++r) {
                int row = r0 + mt * 16 + q * 4 + r;
                float o = fmaxf((acc[mt][nt][r] + bias) * sc + sh, 0.f);
                out[(size_t)row * DIM + col] = o;
                if (xb_out) xb_out[(size_t)row * DIM + col] = f2bf(o);
            }
        }
    }
}

// ---------------- global mean pool (batch sorted) ----------------

__global__ __launch_bounds__(128)
void pool_kernel(const float* __restrict__ x, const int* __restrict__ batch,
                 float* __restrict__ g) {
    __shared__ int s_lo, s_hi;
    int gid = blockIdx.x;
    int d = threadIdx.x;
    if (d == 0) {
        int lo = 0, hi = N_NODES;
        while (lo < hi) { int mid = (lo + hi) >> 1; if (batch[mid] < gid) lo = mid + 1; else hi = mid; }
        s_lo = lo;
        lo = 0; hi = N_NODES;
        while (lo < hi) { int mid = (lo + hi) >> 1; if (batch[mid] < gid + 1) lo = mid + 1; else hi = mid; }
        s_hi = lo;
    }
    __syncthreads();
    int lo = s_lo, hi = s_hi;
    float acc = 0.f;
    for (int n = lo; n < hi; ++n) acc += x[n * DIM + d];
    float cnt = fmaxf((float)(hi - lo), 1.0f);
    g[gid * DIM + d] = acc / cnt;
}

// ---------------- head ----------------

__global__ __launch_bounds__(128)
void head1_kernel(const float* __restrict__ g, const float* __restrict__ W1,
                  const float* __restrict__ b1, float* __restrict__ h1) {
    __shared__ float gs[DIM];
    int gid = blockIdx.x, c = threadIdx.x;
    gs[c] = g[gid * DIM + c];
    __syncthreads();
    float acc = b1[c];
    for (int k = 0; k < DIM; ++k) acc += gs[k] * W1[k * DIM + c];
    h1[gid * DIM + c] = fmaxf(acc, 0.f);
}

__global__ __launch_bounds__(64)
void head2_kernel(const float* __restrict__ h1, const float* __restrict__ W2,
                  const float* __restrict__ b2, float* __restrict__ out) {
    __shared__ float hs[DIM];
    int gid = blockIdx.x;
    int t = threadIdx.x;
    hs[t] = h1[gid * DIM + t];
    hs[t + 64] = h1[gid * DIM + t + 64];
    __syncthreads();
    if (t < NCLASS) {
        float acc = b2[t];
        for (int k = 0; k < DIM; ++k) acc += hs[k] * W2[k * NCLASS + t];
        out[gid * NCLASS + t] = acc;
    }
}

// ---------------- launch ----------------

extern "C" void kernel_launch(void* const* d_in, const int* in_sizes, int n_in,
                              void* d_out, int out_size, void* d_ws, size_t ws_size,
                              hipStream_t stream) {
    const float* edge_attr = (const float*)d_in[0];
    const int*   edge_index = (const int*)d_in[1];
    const int*   batch = (const int*)d_in[2];
    const float* node_emb = (const float*)d_in[3];
    const float* edge_W = (const float*)d_in[4];
    const float* edge_b = (const float*)d_in[5];
    const float* mlp_W1 = (const float*)d_in[6];
    const float* mlp_b1 = (const float*)d_in[7];
    const float* bn1_g = (const float*)d_in[8];
    const float* bn1_b = (const float*)d_in[9];
    const float* bn1_m = (const float*)d_in[10];
    const float* bn1_v = (const float*)d_in[11];
    const float* mlp_W2 = (const float*)d_in[12];
    const float* mlp_b2 = (const float*)d_in[13];
    const float* bn2_g = (const float*)d_in[14];
    const float* bn2_b = (const float*)d_in[15];
    const float* bn2_m = (const float*)d_in[16];
    const float* bn2_v = (const float*)d_in[17];
    const float* head_W1 = (const float*)d_in[18];
    const float* head_b1 = (const float*)d_in[19];
    const float* head_W2 = (const float*)d_in[20];
    const float* head_b2 = (const float*)d_in[21];
    float* out = (float*)d_out;

    const int* src = edge_index;
    const int* dst = edge_index + N_EDGES;

    size_t off = 0;
    auto carve = [&](size_t bytes) {
        void* p = (char*)d_ws + off;
        off += (bytes + 255) & ~(size_t)255;
        return p;
    };
    float* x            = (float*)carve((size_t)N_PAD * DIM * 4);
    unsigned short* xb  = (unsigned short*)carve((size_t)N_PAD * DIM * 2);
    float* h            = (float*)carve((size_t)N_PAD * DIM * 4);
    unsigned short* ea8 = (unsigned short*)carve((size_t)N_EDGES * 8 * 2);
    unsigned short* Wthi = (unsigned short*)carve((size_t)2 * LAYERS * DIM * DIM * 2);
    unsigned short* Wtlo = (unsigned short*)carve((size_t)2 * LAYERS * DIM * DIM * 2);
    int* deg      = (int*)carve((size_t)N_NODES * 4);
    int* row_off  = (int*)carve((size_t)(N_NODES + 1) * 4);
    int* csr      = (int*)carve((size_t)N_EDGES * 4);
    float* gbuf   = (float*)carve((size_t)N_GRAPHS * DIM * 4);
    float* h1buf  = (float*)carve((size_t)N_GRAPHS * DIM * 4);
    (void)ws_size;

    zero_ints<<<(N_NODES + 255) / 256, 256, 0, stream>>>(deg, N_NODES);
    hist_kernel<<<(N_EDGES + 255) / 256, 256, 0, stream>>>(dst, deg);
    scan_kernel<<<1, 1024, 0, stream>>>(deg, row_off);
    zero_ints<<<(N_NODES + 255) / 256, 256, 0, stream>>>(deg, N_NODES);
    fill_csr<<<(N_EDGES + 255) / 256, 256, 0, stream>>>(dst, row_off, deg, csr);

    init_x<<<(N_NODES * DIM + 255) / 256, 256, 0, stream>>>(x, xb, node_emb);
    prep_ea<<<(N_EDGES * 8 + 255) / 256, 256, 0, stream>>>(edge_attr, ea8);
    prep_w<<<(2 * LAYERS * DIM * DIM + 255) / 256, 256, 0, stream>>>(mlp_W1, mlp_W2, Wthi, Wtlo);

    const int gemm_blocks = N_PAD / TM;   // 782
    for (int l = 0; l < LAYERS; ++l) {
        aggregate<<<N_NODES / NB, 256, 0, stream>>>(
            x, xb, h, ea8, src, csr, row_off,
            edge_W + (size_t)l * EDIM * DIM, edge_b + (size_t)l * DIM);
        gemm_mfma<<<gemm_blocks, 256, 0, stream>>>(
            h, h,
            Wthi + ((size_t)l << 14), Wtlo + ((size_t)l << 14),
            mlp_b1 + (size_t)l * DIM,
            bn1_g + (size_t)l * DIM, bn1_b + (size_t)l * DIM,
            bn1_m + (size_t)l * DIM, bn1_v + (size_t)l * DIM,
            nullptr);
        gemm_mfma<<<gemm_blocks, 256, 0, stream>>>(
            h, x,
            Wthi + ((size_t)(LAYERS + l) << 14), Wtlo + ((size_t)(LAYERS + l) << 14),
            mlp_b2 + (size_t)l * DIM,
            bn2_g + (size_t)l * DIM, bn2_b + (size_t)l * DIM,
            bn2_m + (size_t)l * DIM, bn2_v + (size_t)l * DIM,
            xb);
    }

    pool_kernel<<<N_GRAPHS, 128, 0, stream>>>(x, batch, gbuf);
    head1_kernel<<<N_GRAPHS, 128, 0, stream>>>(gbuf, head_W1, head_b1, h1buf);
    head2_kernel<<<N_GRAPHS, 64, 0, stream>>>(h1buf, head_W2, head_b2, out);
}